// Round 1
// 429.663 us; speedup vs baseline: 1.0100x; 1.0100x over previous
//
#include <hip/hip_runtime.h>
#include <hip/hip_bf16.h>

#define H 224
#define W 224
#define C 256
#define F 256
#define OB 14

typedef __attribute__((ext_vector_type(8))) short short8;
typedef __attribute__((ext_vector_type(4))) float f32x4;

__device__ __forceinline__ unsigned short f2bf(float f) {
    union { float f; unsigned u; } v; v.f = f;
    unsigned r = v.u + 0x7fffu + ((v.u >> 16) & 1u);
    return (unsigned short)(r >> 16);
}

// ---------------------------------------------------------------------------
// Weight repack: kernel[ky][kx][c][f] fp32  ->  bf16 B-fragment-major layout
// wrep[((kt*16 + nt)*64 + lane)*8 + j] = bf16(w[kk][c32*32 + quad*8 + j][nt*16 + lq])
// ---------------------------------------------------------------------------
__global__ __launch_bounds__(256) void repack_kernel(const float* __restrict__ wsrc,
                                                     unsigned short* __restrict__ wrep) {
    int g = blockIdx.x * 256 + threadIdx.x;   // < 72*16*64 = 73728
    int lane = g & 63;
    int nt   = (g >> 6) & 15;
    int kt   = g >> 10;
    int kk   = kt >> 3, c32 = kt & 7;
    int quad = lane >> 4, lq = lane & 15;
    int cbase = c32 * 32 + quad * 8;
    int f = nt * 16 + lq;
    alignas(16) unsigned short tmp[8];
#pragma unroll
    for (int j = 0; j < 8; ++j) {
        tmp[j] = f2bf(wsrc[((size_t)(kk * 256 + cbase + j)) * 256 + f]);
    }
    *reinterpret_cast<uint4*>(wrep + (size_t)g * 8) = *reinterpret_cast<const uint4*>(tmp);
}

__global__ void init_kernel(int* __restrict__ cnt) {
    cnt[0] = 0;
    cnt[1] = 0;
}

// ---------------------------------------------------------------------------
// Flags + compaction: active block ids packed to front of list, inactive to back.
// ---------------------------------------------------------------------------
__global__ __launch_bounds__(256) void flags_kernel(const float* __restrict__ mask,
                                                    int* __restrict__ list,
                                                    int* __restrict__ cnt) {
    int b = blockIdx.x;                 // (n, by, bx)
    int n = b >> 8, by = (b >> 4) & 15, bx = b & 15;
    int t = threadIdx.x;
    int r = t >> 4, s = t & 15;
    int gy = by * OB - 1 + r, gx = bx * OB - 1 + s;
    float v = 0.f;
    if ((unsigned)gy < (unsigned)H && (unsigned)gx < (unsigned)W)
        v = mask[((size_t)n * H + gy) * W + gx];
    __shared__ float red[256];
    red[t] = v;
    __syncthreads();
    if (t < 64) {
        float x = red[t] + red[t + 64] + red[t + 128] + red[t + 192];
#pragma unroll
        for (int off = 32; off; off >>= 1) x += __shfl_down(x, off);
        if (t == 0) {
            if (x > 0.5f * 256.0f) {
                int p = atomicAdd(&cnt[0], 1);
                list[p] = b;
            } else {
                int p = atomicAdd(&cnt[1], 1);
                list[1023 - p] = b;
            }
        }
    }
}

// ---------------------------------------------------------------------------
// Conv v2: occupancy + pipeline restructure.
//   Old: 512 thr, acc[7][4] (56 VGPR + 112 AGPR ~ 200/wave) -> 2 waves/SIMD,
//        2 serial stage->compute phases -> MfmaUtil 27%.
//   New: 1024 thr = 16 waves (2 wm x 8 wn), per-wave 7 rows x 32 f:
//        acc[7][2] = 56 regs -> fits <=128/wave (__launch_bounds__(1024,4))
//        -> 4 waves/SIMD.
//   4 channel chunks of 64, double-buffered 32KB LDS halves (total 64KB):
//        issue global loads for chunk cc+1 before compute (T14), write-through
//        to the idle half after the kx=0 group, ONE barrier per chunk.
//   Rolling-row MFMA schedule: per (kx,c32l) hold b[3ky][2nt] in regs and read
//        9 A-frags (rows wm*7 .. wm*7+8) once each -> each ds_read feeds all
//        3 ky taps (9 reads per group vs 21) -> LDS timeline ~41K cyc/block
//        << MFMA 78K cyc/SIMD/block.
//   LDS swizzle re-derived for 64-ch rows (8 granules of 16B = exactly 32
//        banks): granule ^= (pix & 7); both ds_write_b64 and ds_read_b128 are
//        bank-balanced.
// ---------------------------------------------------------------------------
__global__ __launch_bounds__(1024, 4) void conv_kernel(const float* __restrict__ in,
                                                       const unsigned short* __restrict__ wrep,
                                                       const float* __restrict__ bias,
                                                       const int* __restrict__ list,
                                                       const int* __restrict__ cnt,
                                                       float* __restrict__ out) {
    __shared__ __align__(16) unsigned short patch[2][256 * 64];  // 2 x 32 KB

    const int bid = blockIdx.x;
    const int n_active = cnt[0];
    const int b = list[bid];
    const int n = b >> 8, by = (b >> 4) & 15, bx = b & 15;
    const int tid = threadIdx.x;
    const int gy0 = by * OB - 1, gx0 = bx * OB - 1;
    float* outB = out + (size_t)n * H * W * F;

    if (bid >= n_active) {
#pragma unroll 4
        for (int idx = tid; idx < 196 * 64; idx += 1024) {
            int pix = idx >> 6, fv = idx & 63;
            int oy = pix / 14, ox = pix - oy * 14;
            size_t o = ((size_t)((by * OB + oy) * W + bx * OB + ox)) * F + fv * 4;
            *reinterpret_cast<float4*>(outB + o) = make_float4(0.f, 0.f, 0.f, 0.f);
        }
        return;
    }

    const int wave = tid >> 6, lane = tid & 63;
    const int quad = lane >> 4, lq = lane & 15;
    const int wm = wave >> 3;          // 0..1 : rows wm*7 .. wm*7+6
    const int wn = wave & 7;           // 0..7 : f-tiles nt = wn*2, wn*2+1

    const float* inB = in + (size_t)n * H * W * C;

    // Per-thread staging geometry (constant across chunks; only channel offset
    // changes). Each thread stages 4 uint2 units (4 ch each) per 64-ch chunk.
    const float* sp[4];
    int so[4];
#pragma unroll
    for (int it = 0; it < 4; ++it) {
        int idx = tid + (it << 10);          // 0..4095
        int pix = idx >> 4, chv = idx & 15;  // pixel 0..255, 4-ch unit 0..15
        int rr = pix >> 4, ss = pix & 15;
        int gy = gy0 + rr, gx = gx0 + ss;
        bool ok = ((unsigned)gy < (unsigned)H) && ((unsigned)gx < (unsigned)W);
        sp[it] = ok ? (inB + ((size_t)(gy * W + gx)) * C + chv * 4) : nullptr;
        so[it] = (pix << 6) + (((chv >> 1) ^ (pix & 7)) << 3) + ((chv & 1) << 2);
    }

    f32x4 acc[7][2];
#pragma unroll
    for (int r = 0; r < 7; ++r) {
        acc[r][0] = (f32x4)(0.f);
        acc[r][1] = (f32x4)(0.f);
    }

    const int scol_base = (lq > 13) ? 13 : lq;   // clamp garbage M lanes
    const unsigned short* wb = wrep + ((size_t)(wn * 2) * 64 + lane) * 8;
    const int arow_base = (wm * 7 * 16) << 6;    // elem offset of wave's row-0

    // prologue: stage chunk 0 into patch[0]
#pragma unroll
    for (int it = 0; it < 4; ++it) {
        float4 v = make_float4(0.f, 0.f, 0.f, 0.f);
        if (sp[it]) v = *reinterpret_cast<const float4*>(sp[it]);
        uint2 bb;
        bb.x = (unsigned)f2bf(v.x) | ((unsigned)f2bf(v.y) << 16);
        bb.y = (unsigned)f2bf(v.z) | ((unsigned)f2bf(v.w) << 16);
        *reinterpret_cast<uint2*>(&patch[0][so[it]]) = bb;
    }
    __syncthreads();

    int cur = 0;
#pragma unroll 1
    for (int cc = 0; cc < 4; ++cc) {
        const bool pf = (cc < 3);
        float4 st[4];
        if (pf) {
            // issue next-chunk loads early; consumed after the kx=0 group
#pragma unroll
            for (int it = 0; it < 4; ++it) {
                st[it] = make_float4(0.f, 0.f, 0.f, 0.f);
                if (sp[it]) st[it] = *reinterpret_cast<const float4*>(sp[it] + (cc + 1) * 64);
            }
        }
        const unsigned short* pc = &patch[cur][0];
#pragma unroll 1
        for (int kx = 0; kx < 3; ++kx) {
            const int scol = scol_base + kx;     // <= 15
            const int sw = scol & 7;
            const int acol = arow_base + (scol << 6);
#pragma unroll 1
            for (int c32l = 0; c32l < 2; ++c32l) {
                const unsigned short* ap = pc + acol + ((((c32l << 2) + quad) ^ sw) << 3);
                const unsigned short* wbk = wb + (cc * 2 + c32l) * 8192 + kx * 65536;
                short8 bf[3][2];
#pragma unroll
                for (int ky = 0; ky < 3; ++ky) {
                    bf[ky][0] = *reinterpret_cast<const short8*>(wbk + ky * 196608);
                    bf[ky][1] = *reinterpret_cast<const short8*>(wbk + ky * 196608 + 512);
                }
                __builtin_amdgcn_s_setprio(1);
#pragma unroll
                for (int rowl = 0; rowl < 9; ++rowl) {
                    short8 a = *reinterpret_cast<const short8*>(ap + (rowl << 10));
#pragma unroll
                    for (int ky = 0; ky < 3; ++ky) {
                        const int r = rowl - ky;
                        if (r >= 0 && r < 7) {
                            acc[r][0] = __builtin_amdgcn_mfma_f32_16x16x32_bf16(a, bf[ky][0], acc[r][0], 0, 0, 0);
                            acc[r][1] = __builtin_amdgcn_mfma_f32_16x16x32_bf16(a, bf[ky][1], acc[r][1], 0, 0, 0);
                        }
                    }
                }
                __builtin_amdgcn_s_setprio(0);
            }
            if (kx == 0 && pf) {
                // write-through next chunk into the idle LDS half; safe before
                // the barrier (that half was released by last chunk's barrier)
#pragma unroll
                for (int it = 0; it < 4; ++it) {
                    uint2 bb;
                    bb.x = (unsigned)f2bf(st[it].x) | ((unsigned)f2bf(st[it].y) << 16);
                    bb.y = (unsigned)f2bf(st[it].z) | ((unsigned)f2bf(st[it].w) << 16);
                    *reinterpret_cast<uint2*>(&patch[cur ^ 1][so[it]]) = bb;
                }
            }
        }
        if (pf) {
            __syncthreads();
            cur ^= 1;
        }
    }

    // Epilogue. D layout: M-index (output col ox) = quad*4 + reg, N-index = lq.
    const float bv0 = bias[wn * 32 + lq];
    const float bv1 = bias[wn * 32 + 16 + lq];
#pragma unroll
    for (int r = 0; r < 7; ++r) {
        const int oy = wm * 7 + r;
#pragma unroll
        for (int j = 0; j < 4; ++j) {
            const int ox = quad * 4 + j;
            if (ox < 14) {
                size_t o = ((size_t)((by * OB + oy) * W + bx * OB + ox)) * F + wn * 32 + lq;
                float v0 = acc[r][0][j] + bv0;
                float v1 = acc[r][1][j] + bv1;
                outB[o]      = v0 > 0.f ? v0 : 0.f;
                outB[o + 16] = v1 > 0.f ? v1 : 0.f;
            }
        }
    }
}

extern "C" void kernel_launch(void* const* d_in, const int* in_sizes, int n_in,
                              void* d_out, int out_size, void* d_ws, size_t ws_size,
                              hipStream_t stream) {
    const float* inputs = (const float*)d_in[0];
    const float* mask   = (const float*)d_in[1];
    const float* wsrc   = (const float*)d_in[2];
    const float* bias   = (const float*)d_in[3];
    float* outp = (float*)d_out;

    unsigned short* wrep = (unsigned short*)d_ws;              // 1,179,648 B
    int* list = (int*)((char*)d_ws + 1179648);                 // 1024 ints
    int* cnt  = (int*)((char*)d_ws + 1179648 + 4096);          // 2 ints

    hipLaunchKernelGGL(init_kernel, dim3(1), dim3(1), 0, stream, cnt);
    hipLaunchKernelGGL(repack_kernel, dim3(288), dim3(256), 0, stream, wsrc, wrep);
    hipLaunchKernelGGL(flags_kernel, dim3(1024), dim3(256), 0, stream, mask, list, cnt);
    hipLaunchKernelGGL(conv_kernel, dim3(1024), dim3(1024), 0, stream,
                       inputs, wrep, bias, list, cnt, outp);
}